// Round 1
// baseline (166.005 us; speedup 1.0000x reference)
//
#include <hip/hip_runtime.h>

#define B_   8
#define C_   512
#define HW_  1024
#define MID_ 64
#define NCOL (B_*HW_)   /* 8192 */
#define NROWS 192
#define EPS  1e-5f

/* ws layout (float offsets) */
#define YOFF  0
#define YSZ   (NROWS*NCOL)            /* 1,572,864 */
#define SSOFF (YOFF+YSZ)              /* scaleF[64] shiftF[64] scaleG[64] shiftG[64] */
#define SSSZ  256
#define CPOFF (SSOFF+SSSZ)            /* partials [8][3][4][64][64] */
#define CPSZ  (8*3*4*64*64)
#define CMOFF (CPOFF+CPSZ)            /* [8][3][64][64] : Cf, Cg, T */
#define CMSZ  (8*3*64*64)
#define ISOFF (CMOFF+CMSZ)            /* inv sigma [8] (padded 16) */
#define ISSZ  16
#define UOFF  (ISOFF+ISSZ)            /* U [8][512][64] */

#define FMA16(a, bb) \
  acc[0][0]+=a.x*bb.x; acc[0][1]+=a.x*bb.y; acc[0][2]+=a.x*bb.z; acc[0][3]+=a.x*bb.w; \
  acc[1][0]+=a.y*bb.x; acc[1][1]+=a.y*bb.y; acc[1][2]+=a.y*bb.z; acc[1][3]+=a.y*bb.w; \
  acc[2][0]+=a.z*bb.x; acc[2][1]+=a.z*bb.y; acc[2][2]+=a.z*bb.z; acc[2][3]+=a.z*bb.w; \
  acc[3][0]+=a.w*bb.x; acc[3][1]+=a.w*bb.y; acc[3][2]+=a.w*bb.z; acc[3][3]+=a.w*bb.w;

/* Y = [Wf;Wg;Wh] @ X + bias.  X[c][n] = x[b][c][hw], n = b*1024+hw */
__global__ __launch_bounds__(256) void k_conv(
    const float* __restrict__ x,
    const float* __restrict__ Wf, const float* __restrict__ bf,
    const float* __restrict__ Wg, const float* __restrict__ bg,
    const float* __restrict__ Wh, const float* __restrict__ bh,
    float* __restrict__ ws)
{
  __shared__ float Wt[32][64];  /* [k][row] */
  __shared__ float Xt[32][64];  /* [k][col] */
  const int ct = blockIdx.x;            /* 0..127 col tile */
  const int rt = blockIdx.y;            /* 0..2 which matrix */
  const float* W    = (rt==0) ? Wf : (rt==1) ? Wg : Wh;
  const float* bias = (rt==0) ? bf : (rt==1) ? bg : bh;
  const int n0  = ct*64;
  const int b   = n0 >> 10;
  const int hw0 = n0 & 1023;
  const int t  = threadIdx.x;
  const int ti = t >> 4, tj = t & 15;
  float acc[4][4] = {};
  for (int kk = 0; kk < C_; kk += 32) {
    for (int q = t; q < 512; q += 256) {
      const int row = q >> 3;
      const int k4  = (q & 7) * 4;
      const float4 wv = *reinterpret_cast<const float4*>(&W[row*C_ + kk + k4]);
      Wt[k4+0][row] = wv.x; Wt[k4+1][row] = wv.y; Wt[k4+2][row] = wv.z; Wt[k4+3][row] = wv.w;
    }
    for (int q = t; q < 512; q += 256) {
      const int kl = q >> 4;
      const int c4 = (q & 15) * 4;
      const float4 xv = *reinterpret_cast<const float4*>(
          &x[((size_t)b*C_ + (size_t)(kk + kl))*HW_ + hw0 + c4]);
      *reinterpret_cast<float4*>(&Xt[kl][c4]) = xv;
    }
    __syncthreads();
    #pragma unroll
    for (int k = 0; k < 32; ++k) {
      const float4 a  = *reinterpret_cast<const float4*>(&Wt[k][ti*4]);
      const float4 bb = *reinterpret_cast<const float4*>(&Xt[k][tj*4]);
      FMA16(a, bb)
    }
    __syncthreads();
  }
  const int r0 = rt*64;
  #pragma unroll
  for (int i = 0; i < 4; ++i) {
    const int rl = ti*4 + i;
    const float bi = bias[rl];
    float4 o; o.x = acc[i][0]+bi; o.y = acc[i][1]+bi; o.z = acc[i][2]+bi; o.w = acc[i][3]+bi;
    *reinterpret_cast<float4*>(&ws[YOFF + (size_t)(r0+rl)*NCOL + n0 + tj*4]) = o;
  }
}

/* per-row mean/var over 8192 cols for rows 0..127, fold BN into scale/shift */
__global__ __launch_bounds__(256) void k_stats(
    const float* __restrict__ gamma_f, const float* __restrict__ beta_f,
    const float* __restrict__ gamma_g, const float* __restrict__ beta_g,
    float* __restrict__ ws)
{
  const int r = blockIdx.x;   /* 0..127 */
  const float* Yr = ws + YOFF + (size_t)r*NCOL;
  const int t = threadIdx.x;
  float s = 0.f, s2 = 0.f;
  for (int n = t; n < NCOL; n += 256) { const float v = Yr[n]; s += v; s2 += v*v; }
  __shared__ float sh[256], sh2[256];
  sh[t] = s; sh2[t] = s2;
  __syncthreads();
  for (int st = 128; st > 0; st >>= 1) {
    if (t < st) { sh[t] += sh[t+st]; sh2[t] += sh2[t+st]; }
    __syncthreads();
  }
  if (t == 0) {
    const float mean = sh[0] * (1.0f/NCOL);
    const float var  = sh2[0] * (1.0f/NCOL) - mean*mean;
    float g, be; int j;
    if (r < 64) { j = r;     g = gamma_f[j]; be = beta_f[j]; }
    else        { j = r-64;  g = gamma_g[j]; be = beta_g[j]; }
    const float sc = g * rsqrtf(var + EPS);
    const float sf = be - mean*sc;
    if (r < 64) { ws[SSOFF + j]       = sc; ws[SSOFF + 64  + j] = sf; }
    else        { ws[SSOFF + 128 + j] = sc; ws[SSOFF + 192 + j] = sf; }
  }
}

/* partial 64x64 products per (batch, which, chunk): which 0:Cf=F F^T 1:Cg=G G^T 2:T=H G^T */
__global__ __launch_bounds__(256) void k_cpart(float* __restrict__ ws)
{
  __shared__ float Al[32][64];  /* [n_local][row] */
  __shared__ float Bl[32][64];
  const int chunk = blockIdx.x, which = blockIdx.y, b = blockIdx.z;
  const float* Y   = ws + YOFF;
  const float* scF = ws + SSOFF,       *sfF = ws + SSOFF + 64;
  const float* scG = ws + SSOFF + 128, *sfG = ws + SSOFF + 192;
  const int ybaseA = (which==0) ? 0 : (which==1) ? 64 : 128;
  const int ybaseB = (which==0) ? 0 : 64;
  const bool bnA = (which != 2);
  const float* scA = (which==0) ? scF : scG;  const float* sfA = (which==0) ? sfF : sfG;
  const float* scB = (which==0) ? scF : scG;  const float* sfB = (which==0) ? sfF : sfG;
  const int ncol0 = b*1024 + chunk*256;
  const int t = threadIdx.x;
  const int ti = t >> 4, tj = t & 15;
  float acc[4][4] = {};
  for (int cc = 0; cc < 256; cc += 32) {
    for (int q = t; q < 512; q += 256) {
      const int row = q >> 3;
      const int c4  = (q & 7) * 4;
      const float4 yv = *reinterpret_cast<const float4*>(
          &Y[(size_t)(ybaseA+row)*NCOL + ncol0 + cc + c4]);
      float v0, v1, v2, v3;
      if (bnA) {
        const float s = scA[row], f = sfA[row];
        v0 = fmaxf(s*yv.x+f, 0.f); v1 = fmaxf(s*yv.y+f, 0.f);
        v2 = fmaxf(s*yv.z+f, 0.f); v3 = fmaxf(s*yv.w+f, 0.f);
      } else { v0 = yv.x; v1 = yv.y; v2 = yv.z; v3 = yv.w; }
      Al[c4+0][row]=v0; Al[c4+1][row]=v1; Al[c4+2][row]=v2; Al[c4+3][row]=v3;
    }
    for (int q = t; q < 512; q += 256) {
      const int row = q >> 3;
      const int c4  = (q & 7) * 4;
      const float4 yv = *reinterpret_cast<const float4*>(
          &Y[(size_t)(ybaseB+row)*NCOL + ncol0 + cc + c4]);
      const float s = scB[row], f = sfB[row];
      Bl[c4+0][row]=fmaxf(s*yv.x+f,0.f); Bl[c4+1][row]=fmaxf(s*yv.y+f,0.f);
      Bl[c4+2][row]=fmaxf(s*yv.z+f,0.f); Bl[c4+3][row]=fmaxf(s*yv.w+f,0.f);
    }
    __syncthreads();
    #pragma unroll
    for (int n = 0; n < 32; ++n) {
      const float4 a  = *reinterpret_cast<const float4*>(&Al[n][ti*4]);
      const float4 bb = *reinterpret_cast<const float4*>(&Bl[n][tj*4]);
      FMA16(a, bb)
    }
    __syncthreads();
  }
  const size_t obase = CPOFF + (size_t)((b*3+which)*4 + chunk)*4096;
  #pragma unroll
  for (int i = 0; i < 4; ++i) {
    float4 o; o.x = acc[i][0]; o.y = acc[i][1]; o.z = acc[i][2]; o.w = acc[i][3];
    *reinterpret_cast<float4*>(&ws[obase + (size_t)(ti*4+i)*64 + tj*4]) = o;
  }
}

__global__ __launch_bounds__(256) void k_creduce(float* __restrict__ ws)
{
  const int m = blockIdx.x;   /* 0..23 = b*3+which */
  for (int e = threadIdx.x; e < 4096; e += 256) {
    float s = 0.f;
    #pragma unroll
    for (int ch = 0; ch < 4; ++ch) s += ws[CPOFF + (size_t)(m*4+ch)*4096 + e];
    ws[CMOFF + (size_t)m*4096 + e] = s;
  }
}

/* per batch: M = Cg @ Cf, power iteration -> 1/sigma */
__global__ __launch_bounds__(64) void k_sigma(float* __restrict__ ws)
{
  const int b = blockIdx.x;
  const int lane = threadIdx.x;
  const float* Cf = ws + CMOFF + (size_t)(b*3+0)*4096;
  const float* Cg = ws + CMOFF + (size_t)(b*3+1)*4096;
  __shared__ float CfL[64][64];
  __shared__ float vsh[64];
  for (int q = lane; q < 1024; q += 64)
    *(reinterpret_cast<float4*>(&CfL[0][0]) + q) = *(reinterpret_cast<const float4*>(Cf) + q);
  __syncthreads();
  float Mrow[64];
  #pragma unroll
  for (int j = 0; j < 64; ++j) Mrow[j] = 0.f;
  for (int k = 0; k < 64; ++k) {
    const float cg = Cg[lane*64 + k];
    #pragma unroll
    for (int j4 = 0; j4 < 16; ++j4) {
      const float4 cf = *reinterpret_cast<const float4*>(&CfL[k][j4*4]);
      Mrow[j4*4+0] += cg*cf.x; Mrow[j4*4+1] += cg*cf.y;
      Mrow[j4*4+2] += cg*cf.z; Mrow[j4*4+3] += cg*cf.w;
    }
  }
  vsh[lane] = 1.0f;
  __syncthreads();
  float lambda = 0.f;
  for (int it = 0; it < 80; ++it) {
    float w0 = 0.f, w1 = 0.f, w2 = 0.f, w3 = 0.f;
    #pragma unroll
    for (int j4 = 0; j4 < 16; ++j4) {
      const float4 vq = *reinterpret_cast<const float4*>(&vsh[j4*4]);
      w0 += Mrow[j4*4+0]*vq.x; w1 += Mrow[j4*4+1]*vq.y;
      w2 += Mrow[j4*4+2]*vq.z; w3 += Mrow[j4*4+3]*vq.w;
    }
    float w = (w0+w1) + (w2+w3);
    float num = vsh[lane] * w;
    #pragma unroll
    for (int off = 32; off > 0; off >>= 1) num += __shfl_xor(num, off);
    lambda = num;                    /* Rayleigh: v normalized from prev iter */
    float n2 = w*w;
    #pragma unroll
    for (int off = 32; off > 0; off >>= 1) n2 += __shfl_xor(n2, off);
    const float rn = rsqrtf(fmaxf(n2, 1e-30f));
    __syncthreads();
    vsh[lane] = w * rn;
    __syncthreads();
  }
  if (lane == 0) ws[ISOFF + b] = rsqrtf(fmaxf(lambda, 1e-30f));  /* 1/sigma */
}

/* U_b = (Wv @ T_b) * inv_sigma_b   [512 x 64] */
__global__ __launch_bounds__(256) void k_ufold(const float* __restrict__ Wv, float* __restrict__ ws)
{
  __shared__ float Wt[64][64];  /* [c][row] */
  __shared__ float Tl[64][64];  /* [c][k] row-major */
  const int rt = blockIdx.x, b = blockIdx.y;
  const float* T = ws + CMOFF + (size_t)(b*3+2)*4096;
  const float isig = ws[ISOFF + b];
  const int t = threadIdx.x;
  const int ti = t >> 4, tj = t & 15;
  for (int q = t; q < 1024; q += 256)
    *(reinterpret_cast<float4*>(&Tl[0][0]) + q) = *(reinterpret_cast<const float4*>(T) + q);
  for (int q = t; q < 1024; q += 256) {
    const int row = q >> 4;
    const int c4  = (q & 15) * 4;
    const float4 wv = *reinterpret_cast<const float4*>(&Wv[(size_t)(rt*64+row)*64 + c4]);
    Wt[c4+0][row]=wv.x; Wt[c4+1][row]=wv.y; Wt[c4+2][row]=wv.z; Wt[c4+3][row]=wv.w;
  }
  __syncthreads();
  float acc[4][4] = {};
  #pragma unroll
  for (int c = 0; c < 64; ++c) {
    const float4 a  = *reinterpret_cast<const float4*>(&Wt[c][ti*4]);
    const float4 bb = *reinterpret_cast<const float4*>(&Tl[c][tj*4]);
    FMA16(a, bb)
  }
  #pragma unroll
  for (int i = 0; i < 4; ++i) {
    float4 o; o.x = acc[i][0]*isig; o.y = acc[i][1]*isig; o.z = acc[i][2]*isig; o.w = acc[i][3]*isig;
    *reinterpret_cast<float4*>(&ws[UOFF + ((size_t)b*512 + rt*64 + ti*4+i)*64 + tj*4]) = o;
  }
}

/* out = U_b @ F_b + bv + x   per batch */
__global__ __launch_bounds__(256) void k_final(
    const float* __restrict__ x, const float* __restrict__ bv,
    float* __restrict__ out, const float* __restrict__ ws)
{
  __shared__ float Ut[64][64];  /* [k][ocrow] */
  __shared__ float Fl[64][64];  /* [k][n] */
  const int nt = blockIdx.x, ot = blockIdx.y, b = blockIdx.z;
  const float* scF = ws + SSOFF; const float* sfF = ws + SSOFF + 64;
  const int t = threadIdx.x;
  const int ti = t >> 4, tj = t & 15;
  for (int q = t; q < 1024; q += 256) {
    const int row = q >> 4;
    const int k4  = (q & 15) * 4;
    const float4 uv = *reinterpret_cast<const float4*>(
        &ws[UOFF + ((size_t)b*512 + ot*64 + row)*64 + k4]);
    Ut[k4+0][row]=uv.x; Ut[k4+1][row]=uv.y; Ut[k4+2][row]=uv.z; Ut[k4+3][row]=uv.w;
  }
  for (int q = t; q < 1024; q += 256) {
    const int k  = q >> 4;
    const int c4 = (q & 15) * 4;
    const float4 yv = *reinterpret_cast<const float4*>(
        &ws[YOFF + (size_t)k*NCOL + b*1024 + nt*64 + c4]);
    const float s = scF[k], f = sfF[k];
    Fl[k][c4+0]=fmaxf(s*yv.x+f,0.f); Fl[k][c4+1]=fmaxf(s*yv.y+f,0.f);
    Fl[k][c4+2]=fmaxf(s*yv.z+f,0.f); Fl[k][c4+3]=fmaxf(s*yv.w+f,0.f);
  }
  __syncthreads();
  float acc[4][4] = {};
  #pragma unroll
  for (int k = 0; k < 64; ++k) {
    const float4 a  = *reinterpret_cast<const float4*>(&Ut[k][ti*4]);
    const float4 bb = *reinterpret_cast<const float4*>(&Fl[k][tj*4]);
    FMA16(a, bb)
  }
  #pragma unroll
  for (int i = 0; i < 4; ++i) {
    const int oc = ot*64 + ti*4 + i;
    const float bvv = bv[oc];
    const size_t base = ((size_t)b*C_ + oc)*HW_ + nt*64 + tj*4;
    const float4 xv = *reinterpret_cast<const float4*>(&x[base]);
    float4 o;
    o.x = acc[i][0]+bvv+xv.x; o.y = acc[i][1]+bvv+xv.y;
    o.z = acc[i][2]+bvv+xv.z; o.w = acc[i][3]+bvv+xv.w;
    *reinterpret_cast<float4*>(&out[base]) = o;
  }
}

extern "C" void kernel_launch(void* const* d_in, const int* in_sizes, int n_in,
                              void* d_out, int out_size, void* d_ws, size_t ws_size,
                              hipStream_t stream) {
  (void)in_sizes; (void)n_in; (void)out_size; (void)ws_size;
  const float* x       = (const float*)d_in[0];
  const float* Wf      = (const float*)d_in[1];
  const float* bf      = (const float*)d_in[2];
  const float* gamma_f = (const float*)d_in[3];
  const float* beta_f  = (const float*)d_in[4];
  const float* Wg      = (const float*)d_in[5];
  const float* bg      = (const float*)d_in[6];
  const float* gamma_g = (const float*)d_in[7];
  const float* beta_g  = (const float*)d_in[8];
  const float* Wh      = (const float*)d_in[9];
  const float* bh      = (const float*)d_in[10];
  const float* Wv      = (const float*)d_in[11];
  const float* bv      = (const float*)d_in[12];
  float* out = (float*)d_out;
  float* ws  = (float*)d_ws;

  k_conv   <<<dim3(128,3),   256, 0, stream>>>(x, Wf, bf, Wg, bg, Wh, bh, ws);
  k_stats  <<<128,           256, 0, stream>>>(gamma_f, beta_f, gamma_g, beta_g, ws);
  k_cpart  <<<dim3(4,3,8),   256, 0, stream>>>(ws);
  k_creduce<<<24,            256, 0, stream>>>(ws);
  k_sigma  <<<8,              64, 0, stream>>>(ws);
  k_ufold  <<<dim3(8,8),     256, 0, stream>>>(Wv, ws);
  k_final  <<<dim3(16,8,8),  256, 0, stream>>>(x, bv, out, ws);
}

// Round 2
// 115.270 us; speedup vs baseline: 1.4401x; 1.4401x over previous
//
#include <hip/hip_runtime.h>

#define B_   8
#define C_   512
#define HW_  1024
#define MID_ 64
#define NCOL (B_*HW_)   /* 8192 */
#define NROWS 192
#define EPS  1e-5f

/* ws layout (float offsets) */
#define YOFF  0
#define YSZ   (NROWS*NCOL)            /* 1,572,864 */
#define SSOFF (YOFF+YSZ)              /* scaleF[64] shiftF[64] scaleG[64] shiftG[64] */
#define SSSZ  256
#define CPOFF (SSOFF+SSSZ)            /* partials [8][3][4][64][64] */
#define CPSZ  (8*3*4*64*64)
#define CMOFF (CPOFF+CPSZ)            /* (unused now, kept for layout stability) */
#define CMSZ  (8*3*64*64)
#define ISOFF (CMOFF+CMSZ)            /* inv sigma [8] (padded 16) */
#define ISSZ  16
#define UOFF  (ISOFF+ISSZ)            /* U [8][512][64] */

#define FMA16(a, bb) \
  acc[0][0]+=a.x*bb.x; acc[0][1]+=a.x*bb.y; acc[0][2]+=a.x*bb.z; acc[0][3]+=a.x*bb.w; \
  acc[1][0]+=a.y*bb.x; acc[1][1]+=a.y*bb.y; acc[1][2]+=a.y*bb.z; acc[1][3]+=a.y*bb.w; \
  acc[2][0]+=a.z*bb.x; acc[2][1]+=a.z*bb.y; acc[2][2]+=a.z*bb.z; acc[2][3]+=a.z*bb.w; \
  acc[3][0]+=a.w*bb.x; acc[3][1]+=a.w*bb.y; acc[3][2]+=a.w*bb.z; acc[3][3]+=a.w*bb.w;

/* Y = [Wf;Wg;Wh] @ X + bias.  X[c][n] = x[b][c][hw], n = b*1024+hw */
__global__ __launch_bounds__(256) void k_conv(
    const float* __restrict__ x,
    const float* __restrict__ Wf, const float* __restrict__ bf,
    const float* __restrict__ Wg, const float* __restrict__ bg,
    const float* __restrict__ Wh, const float* __restrict__ bh,
    float* __restrict__ ws)
{
  __shared__ float Wt[32][64];  /* [k][row] */
  __shared__ float Xt[32][64];  /* [k][col] */
  const int ct = blockIdx.x;            /* 0..127 col tile */
  const int rt = blockIdx.y;            /* 0..2 which matrix */
  const float* W    = (rt==0) ? Wf : (rt==1) ? Wg : Wh;
  const float* bias = (rt==0) ? bf : (rt==1) ? bg : bh;
  const int n0  = ct*64;
  const int b   = n0 >> 10;
  const int hw0 = n0 & 1023;
  const int t  = threadIdx.x;
  const int ti = t >> 4, tj = t & 15;
  float acc[4][4] = {};
  for (int kk = 0; kk < C_; kk += 32) {
    for (int q = t; q < 512; q += 256) {
      const int row = q >> 3;
      const int k4  = (q & 7) * 4;
      const float4 wv = *reinterpret_cast<const float4*>(&W[row*C_ + kk + k4]);
      Wt[k4+0][row] = wv.x; Wt[k4+1][row] = wv.y; Wt[k4+2][row] = wv.z; Wt[k4+3][row] = wv.w;
    }
    for (int q = t; q < 512; q += 256) {
      const int kl = q >> 4;
      const int c4 = (q & 15) * 4;
      const float4 xv = *reinterpret_cast<const float4*>(
          &x[((size_t)b*C_ + (size_t)(kk + kl))*HW_ + hw0 + c4]);
      *reinterpret_cast<float4*>(&Xt[kl][c4]) = xv;
    }
    __syncthreads();
    #pragma unroll
    for (int k = 0; k < 32; ++k) {
      const float4 a  = *reinterpret_cast<const float4*>(&Wt[k][ti*4]);
      const float4 bb = *reinterpret_cast<const float4*>(&Xt[k][tj*4]);
      FMA16(a, bb)
    }
    __syncthreads();
  }
  const int r0 = rt*64;
  #pragma unroll
  for (int i = 0; i < 4; ++i) {
    const int rl = ti*4 + i;
    const float bi = bias[rl];
    float4 o; o.x = acc[i][0]+bi; o.y = acc[i][1]+bi; o.z = acc[i][2]+bi; o.w = acc[i][3]+bi;
    *reinterpret_cast<float4*>(&ws[YOFF + (size_t)(r0+rl)*NCOL + n0 + tj*4]) = o;
  }
}

/* per-row mean/var over 8192 cols for rows 0..127, fold BN into scale/shift */
__global__ __launch_bounds__(256) void k_stats(
    const float* __restrict__ gamma_f, const float* __restrict__ beta_f,
    const float* __restrict__ gamma_g, const float* __restrict__ beta_g,
    float* __restrict__ ws)
{
  const int r = blockIdx.x;   /* 0..127 */
  const float* Yr = ws + YOFF + (size_t)r*NCOL;
  const int t = threadIdx.x;
  float s = 0.f, s2 = 0.f;
  for (int n = t; n < NCOL; n += 256) { const float v = Yr[n]; s += v; s2 += v*v; }
  __shared__ float sh[256], sh2[256];
  sh[t] = s; sh2[t] = s2;
  __syncthreads();
  for (int st = 128; st > 0; st >>= 1) {
    if (t < st) { sh[t] += sh[t+st]; sh2[t] += sh2[t+st]; }
    __syncthreads();
  }
  if (t == 0) {
    const float mean = sh[0] * (1.0f/NCOL);
    const float var  = sh2[0] * (1.0f/NCOL) - mean*mean;
    float g, be; int j;
    if (r < 64) { j = r;     g = gamma_f[j]; be = beta_f[j]; }
    else        { j = r-64;  g = gamma_g[j]; be = beta_g[j]; }
    const float sc = g * rsqrtf(var + EPS);
    const float sf = be - mean*sc;
    if (r < 64) { ws[SSOFF + j]       = sc; ws[SSOFF + 64  + j] = sf; }
    else        { ws[SSOFF + 128 + j] = sc; ws[SSOFF + 192 + j] = sf; }
  }
}

/* partial 64x64 products per (batch, which, chunk): which 0:Cf=F F^T 1:Cg=G G^T 2:T=H G^T */
__global__ __launch_bounds__(256) void k_cpart(float* __restrict__ ws)
{
  __shared__ float Al[32][64];  /* [n_local][row] */
  __shared__ float Bl[32][64];
  const int chunk = blockIdx.x, which = blockIdx.y, b = blockIdx.z;
  const float* Y   = ws + YOFF;
  const float* scF = ws + SSOFF,       *sfF = ws + SSOFF + 64;
  const float* scG = ws + SSOFF + 128, *sfG = ws + SSOFF + 192;
  const int ybaseA = (which==0) ? 0 : (which==1) ? 64 : 128;
  const int ybaseB = (which==0) ? 0 : 64;
  const bool bnA = (which != 2);
  const float* scA = (which==0) ? scF : scG;  const float* sfA = (which==0) ? sfF : sfG;
  const float* scB = (which==0) ? scF : scG;  const float* sfB = (which==0) ? sfF : sfG;
  const int ncol0 = b*1024 + chunk*256;
  const int t = threadIdx.x;
  const int ti = t >> 4, tj = t & 15;
  float acc[4][4] = {};
  for (int cc = 0; cc < 256; cc += 32) {
    for (int q = t; q < 512; q += 256) {
      const int row = q >> 3;
      const int c4  = (q & 7) * 4;
      const float4 yv = *reinterpret_cast<const float4*>(
          &Y[(size_t)(ybaseA+row)*NCOL + ncol0 + cc + c4]);
      float v0, v1, v2, v3;
      if (bnA) {
        const float s = scA[row], f = sfA[row];
        v0 = fmaxf(s*yv.x+f, 0.f); v1 = fmaxf(s*yv.y+f, 0.f);
        v2 = fmaxf(s*yv.z+f, 0.f); v3 = fmaxf(s*yv.w+f, 0.f);
      } else { v0 = yv.x; v1 = yv.y; v2 = yv.z; v3 = yv.w; }
      Al[c4+0][row]=v0; Al[c4+1][row]=v1; Al[c4+2][row]=v2; Al[c4+3][row]=v3;
    }
    for (int q = t; q < 512; q += 256) {
      const int row = q >> 3;
      const int c4  = (q & 7) * 4;
      const float4 yv = *reinterpret_cast<const float4*>(
          &Y[(size_t)(ybaseB+row)*NCOL + ncol0 + cc + c4]);
      const float s = scB[row], f = sfB[row];
      Bl[c4+0][row]=fmaxf(s*yv.x+f,0.f); Bl[c4+1][row]=fmaxf(s*yv.y+f,0.f);
      Bl[c4+2][row]=fmaxf(s*yv.z+f,0.f); Bl[c4+3][row]=fmaxf(s*yv.w+f,0.f);
    }
    __syncthreads();
    #pragma unroll
    for (int n = 0; n < 32; ++n) {
      const float4 a  = *reinterpret_cast<const float4*>(&Al[n][ti*4]);
      const float4 bb = *reinterpret_cast<const float4*>(&Bl[n][tj*4]);
      FMA16(a, bb)
    }
    __syncthreads();
  }
  const size_t obase = CPOFF + (size_t)((b*3+which)*4 + chunk)*4096;
  #pragma unroll
  for (int i = 0; i < 4; ++i) {
    float4 o; o.x = acc[i][0]; o.y = acc[i][1]; o.z = acc[i][2]; o.w = acc[i][3];
    *reinterpret_cast<float4*>(&ws[obase + (size_t)(ti*4+i)*64 + tj*4]) = o;
  }
}

/* per batch: power iteration on M = Cg @ Cf without forming M.
   Each lane holds row `lane` of Cf and Cg in registers (chunk-reduced on load).
   v broadcast via same-address LDS reads (conflict-free). One butterfly/iter. */
__global__ __launch_bounds__(64) void k_sigma(float* __restrict__ ws)
{
  const int b = blockIdx.x;
  const int lane = threadIdx.x;
  const float* CfP = ws + CPOFF + (size_t)(b*3+0)*16384;
  const float* CgP = ws + CPOFF + (size_t)(b*3+1)*16384;
  __shared__ float vsh[64];
  __shared__ float ush[64];
  float cfr[64], cgr[64];
  #pragma unroll
  for (int k4 = 0; k4 < 16; ++k4) {
    float ax=0.f, ay=0.f, az=0.f, aw=0.f;
    float cx=0.f, cy=0.f, cz=0.f, cw=0.f;
    #pragma unroll
    for (int ch = 0; ch < 4; ++ch) {
      const float4 fa = *reinterpret_cast<const float4*>(&CfP[ch*4096 + lane*64 + k4*4]);
      const float4 fc = *reinterpret_cast<const float4*>(&CgP[ch*4096 + lane*64 + k4*4]);
      ax+=fa.x; ay+=fa.y; az+=fa.z; aw+=fa.w;
      cx+=fc.x; cy+=fc.y; cz+=fc.z; cw+=fc.w;
    }
    cfr[k4*4+0]=ax; cfr[k4*4+1]=ay; cfr[k4*4+2]=az; cfr[k4*4+3]=aw;
    cgr[k4*4+0]=cx; cgr[k4*4+1]=cy; cgr[k4*4+2]=cz; cgr[k4*4+3]=cw;
  }
  float vloc = 0.125f;
  vsh[lane] = vloc;
  __syncthreads();
  float lambda = 0.f;
  #define NIT 20
  for (int it = 0; it <= NIT; ++it) {
    /* u = Cf @ v  (symmetric, row = lane) */
    float u0=0.f,u1=0.f,u2=0.f,u3=0.f;
    #pragma unroll
    for (int j4 = 0; j4 < 16; ++j4) {
      const float4 vq = *reinterpret_cast<const float4*>(&vsh[j4*4]);
      u0 += cfr[j4*4+0]*vq.x; u1 += cfr[j4*4+1]*vq.y;
      u2 += cfr[j4*4+2]*vq.z; u3 += cfr[j4*4+3]*vq.w;
    }
    ush[lane] = (u0+u1)+(u2+u3);
    __syncthreads();
    /* w = Cg @ u */
    float w0=0.f,w1=0.f,w2=0.f,w3=0.f;
    #pragma unroll
    for (int j4 = 0; j4 < 16; ++j4) {
      const float4 uq = *reinterpret_cast<const float4*>(&ush[j4*4]);
      w0 += cgr[j4*4+0]*uq.x; w1 += cgr[j4*4+1]*uq.y;
      w2 += cgr[j4*4+2]*uq.z; w3 += cgr[j4*4+3]*uq.w;
    }
    const float w = (w0+w1)+(w2+w3);
    if (it == NIT) {
      float num = vloc * w;      /* Rayleigh: v normalized, lambda = v.Mv */
      #pragma unroll
      for (int off = 32; off > 0; off >>= 1) num += __shfl_xor(num, off);
      lambda = num;
    } else {
      float n2 = w*w;
      #pragma unroll
      for (int off = 32; off > 0; off >>= 1) n2 += __shfl_xor(n2, off);
      const float rn = rsqrtf(fmaxf(n2, 1e-30f));
      vloc = w * rn;
      vsh[lane] = vloc;          /* safe: all vsh reads done before ush barrier */
      __syncthreads();
    }
  }
  if (lane == 0) ws[ISOFF + b] = rsqrtf(fmaxf(lambda, 1e-30f));  /* 1/sigma */
}

/* U_b = (Wv @ T_b) * inv_sigma_b   [512 x 64]; T chunk-reduced on load */
__global__ __launch_bounds__(256) void k_ufold(const float* __restrict__ Wv, float* __restrict__ ws)
{
  __shared__ float Wt[64][64];  /* [c][row] */
  __shared__ float Tl[64][64];  /* [c][k] row-major */
  const int rt = blockIdx.x, b = blockIdx.y;
  const float* TP = ws + CPOFF + (size_t)(b*3+2)*16384;
  const float isig = ws[ISOFF + b];
  const int t = threadIdx.x;
  const int ti = t >> 4, tj = t & 15;
  for (int q = t; q < 1024; q += 256) {
    float4 s = *(reinterpret_cast<const float4*>(TP) + q);
    #pragma unroll
    for (int ch = 1; ch < 4; ++ch) {
      const float4 p = *(reinterpret_cast<const float4*>(TP) + ch*1024 + q);
      s.x+=p.x; s.y+=p.y; s.z+=p.z; s.w+=p.w;
    }
    *(reinterpret_cast<float4*>(&Tl[0][0]) + q) = s;
  }
  for (int q = t; q < 1024; q += 256) {
    const int row = q >> 4;
    const int c4  = (q & 15) * 4;
    const float4 wv = *reinterpret_cast<const float4*>(&Wv[(size_t)(rt*64+row)*64 + c4]);
    Wt[c4+0][row]=wv.x; Wt[c4+1][row]=wv.y; Wt[c4+2][row]=wv.z; Wt[c4+3][row]=wv.w;
  }
  __syncthreads();
  float acc[4][4] = {};
  #pragma unroll
  for (int c = 0; c < 64; ++c) {
    const float4 a  = *reinterpret_cast<const float4*>(&Wt[c][ti*4]);
    const float4 bb = *reinterpret_cast<const float4*>(&Tl[c][tj*4]);
    FMA16(a, bb)
  }
  #pragma unroll
  for (int i = 0; i < 4; ++i) {
    float4 o; o.x = acc[i][0]*isig; o.y = acc[i][1]*isig; o.z = acc[i][2]*isig; o.w = acc[i][3]*isig;
    *reinterpret_cast<float4*>(&ws[UOFF + ((size_t)b*512 + rt*64 + ti*4+i)*64 + tj*4]) = o;
  }
}

/* out = U_b @ F_b + bv + x   per batch */
__global__ __launch_bounds__(256) void k_final(
    const float* __restrict__ x, const float* __restrict__ bv,
    float* __restrict__ out, const float* __restrict__ ws)
{
  __shared__ float Ut[64][64];  /* [k][ocrow] */
  __shared__ float Fl[64][64];  /* [k][n] */
  const int nt = blockIdx.x, ot = blockIdx.y, b = blockIdx.z;
  const float* scF = ws + SSOFF; const float* sfF = ws + SSOFF + 64;
  const int t = threadIdx.x;
  const int ti = t >> 4, tj = t & 15;
  for (int q = t; q < 1024; q += 256) {
    const int row = q >> 4;
    const int k4  = (q & 15) * 4;
    const float4 uv = *reinterpret_cast<const float4*>(
        &ws[UOFF + ((size_t)b*512 + ot*64 + row)*64 + k4]);
    Ut[k4+0][row]=uv.x; Ut[k4+1][row]=uv.y; Ut[k4+2][row]=uv.z; Ut[k4+3][row]=uv.w;
  }
  for (int q = t; q < 1024; q += 256) {
    const int k  = q >> 4;
    const int c4 = (q & 15) * 4;
    const float4 yv = *reinterpret_cast<const float4*>(
        &ws[YOFF + (size_t)k*NCOL + b*1024 + nt*64 + c4]);
    const float s = scF[k], f = sfF[k];
    Fl[k][c4+0]=fmaxf(s*yv.x+f,0.f); Fl[k][c4+1]=fmaxf(s*yv.y+f,0.f);
    Fl[k][c4+2]=fmaxf(s*yv.z+f,0.f); Fl[k][c4+3]=fmaxf(s*yv.w+f,0.f);
  }
  __syncthreads();
  float acc[4][4] = {};
  #pragma unroll
  for (int k = 0; k < 64; ++k) {
    const float4 a  = *reinterpret_cast<const float4*>(&Ut[k][ti*4]);
    const float4 bb = *reinterpret_cast<const float4*>(&Fl[k][tj*4]);
    FMA16(a, bb)
  }
  #pragma unroll
  for (int i = 0; i < 4; ++i) {
    const int oc = ot*64 + ti*4 + i;
    const float bvv = bv[oc];
    const size_t base = ((size_t)b*C_ + oc)*HW_ + nt*64 + tj*4;
    const float4 xv = *reinterpret_cast<const float4*>(&x[base]);
    float4 o;
    o.x = acc[i][0]+bvv+xv.x; o.y = acc[i][1]+bvv+xv.y;
    o.z = acc[i][2]+bvv+xv.z; o.w = acc[i][3]+bvv+xv.w;
    *reinterpret_cast<float4*>(&out[base]) = o;
  }
}

extern "C" void kernel_launch(void* const* d_in, const int* in_sizes, int n_in,
                              void* d_out, int out_size, void* d_ws, size_t ws_size,
                              hipStream_t stream) {
  (void)in_sizes; (void)n_in; (void)out_size; (void)ws_size;
  const float* x       = (const float*)d_in[0];
  const float* Wf      = (const float*)d_in[1];
  const float* bf      = (const float*)d_in[2];
  const float* gamma_f = (const float*)d_in[3];
  const float* beta_f  = (const float*)d_in[4];
  const float* Wg      = (const float*)d_in[5];
  const float* bg      = (const float*)d_in[6];
  const float* gamma_g = (const float*)d_in[7];
  const float* beta_g  = (const float*)d_in[8];
  const float* Wh      = (const float*)d_in[9];
  const float* bh      = (const float*)d_in[10];
  const float* Wv      = (const float*)d_in[11];
  const float* bv      = (const float*)d_in[12];
  float* out = (float*)d_out;
  float* ws  = (float*)d_ws;

  k_conv   <<<dim3(128,3),   256, 0, stream>>>(x, Wf, bf, Wg, bg, Wh, bh, ws);
  k_stats  <<<128,           256, 0, stream>>>(gamma_f, beta_f, gamma_g, beta_g, ws);
  k_cpart  <<<dim3(4,3,8),   256, 0, stream>>>(ws);
  k_sigma  <<<8,              64, 0, stream>>>(ws);
  k_ufold  <<<dim3(8,8),     256, 0, stream>>>(Wv, ws);
  k_final  <<<dim3(16,8,8),  256, 0, stream>>>(x, bv, out, ws);
}